// Round 1
// baseline (5308.964 us; speedup 1.0000x reference)
//
#include <hip/hip_runtime.h>

#define NN 20000
#define NE 400000
#define ETILE 16
#define NTILE 16

__device__ __forceinline__ float sigf(float x) { return 1.0f / (1.0f + __expf(-x)); }

// =============== message kernel: per-edge TP + gate, scatter pre-linear sums ===============
__global__ __launch_bounds__(256, 2)
void msg_kernel(const float* __restrict__ nf, const float* __restrict__ ea,
                const int* __restrict__ eidx,
                const float* __restrict__ Wss, const float* __restrict__ Wvv,
                const float* __restrict__ Wsv, const float* __restrict__ Wvs,
                float* __restrict__ agg)
{
    const int e0 = blockIdx.x * ETILE;
    const int t  = threadIdx.x;

    __shared__ float s_es[ETILE][9];
    __shared__ float s_ev[ETILE][25];   // [v*3+k]
    __shared__ float s_xs[ETILE][65];
    __shared__ float s_xv[ETILE][97];   // [u*3+k]
    __shared__ float s_hs[ETILE][97];
    __shared__ float s_hv[ETILE][97];   // [w*3+k]
    __shared__ int   s_row[ETILE];
    __shared__ int   s_col[ETILE];
    __shared__ float s_b1[ETILE * 513]; // t_ss staging, later r-half
    __shared__ float s_b2[ETILE * 257]; // dd staging, later p

    if (t < ETILE) {
        s_row[t] = eidx[e0 + t];
        s_col[t] = eidx[NE + e0 + t];
    }
    for (int i = t; i < ETILE * 32; i += 256) {
        int e = i >> 5, c = i & 31;
        float v = ea[(size_t)(e0 + e) * 32 + c];
        if (c < 8) s_es[e][c] = v; else s_ev[e][c - 8] = v;
    }
    __syncthreads();
    for (int i = t; i < ETILE * 160; i += 256) {
        int e = i / 160, c = i - e * 160;
        float v = nf[(size_t)s_col[e] * 160 + c];
        if (c < 64) s_xs[e][c] = v; else s_xv[e][c - 64] = v;
    }
    __syncthreads();
    // z_ss[e][u*8+v] = xs[u]*es[v]
    for (int i = t; i < ETILE * 512; i += 256) {
        int e = i >> 9, uv = i & 511, u = uv >> 3, v = uv & 7;
        s_b1[e * 513 + uv] = s_xs[e][u] * s_es[e][v];
    }
    // dd[e][u*8+v] = inv_sqrt3 * sum_k xv[u][k]*ev[v][k]
    for (int i = t; i < ETILE * 256; i += 256) {
        int e = i >> 8, uv = i & 255, u = uv >> 3, v = uv & 7;
        float a = s_xv[e][u*3+0] * s_ev[e][v*3+0]
                + s_xv[e][u*3+1] * s_ev[e][v*3+1]
                + s_xv[e][u*3+2] * s_ev[e][v*3+2];
        s_b2[e * 257 + uv] = 0.57735026918962576f * a;
    }
    __syncthreads();

    // GEMM: hs[e][w] = sum_512 z_ss*Wss + sum_256 dd*Wvv, thread = 2 edges x 3 w
    const int eg = t >> 5, ww = t & 31;
    const int ee0 = eg * 2, ee1 = ee0 + 1;
    float a00=0.f,a01=0.f,a02=0.f,a10=0.f,a11=0.f,a12=0.f;
    #pragma unroll 4
    for (int kk = 0; kk < 512; ++kk) {
        float w0 = Wss[kk*96 + ww], w1 = Wss[kk*96 + ww + 32], w2 = Wss[kk*96 + ww + 64];
        float z0 = s_b1[ee0*513 + kk], z1 = s_b1[ee1*513 + kk];
        a00 = fmaf(z0,w0,a00); a01 = fmaf(z0,w1,a01); a02 = fmaf(z0,w2,a02);
        a10 = fmaf(z1,w0,a10); a11 = fmaf(z1,w1,a11); a12 = fmaf(z1,w2,a12);
    }
    #pragma unroll 4
    for (int kk = 0; kk < 256; ++kk) {
        float w0 = Wvv[kk*96 + ww], w1 = Wvv[kk*96 + ww + 32], w2 = Wvv[kk*96 + ww + 64];
        float z0 = s_b2[ee0*257 + kk], z1 = s_b2[ee1*257 + kk];
        a00 = fmaf(z0,w0,a00); a01 = fmaf(z0,w1,a01); a02 = fmaf(z0,w2,a02);
        a10 = fmaf(z1,w0,a10); a11 = fmaf(z1,w1,a11); a12 = fmaf(z1,w2,a12);
    }
    const float NSM = 0.03608439182435161f; // 1/sqrt(768)
    s_hs[ee0][ww] = a00*NSM; s_hs[ee0][ww+32] = a01*NSM; s_hs[ee0][ww+64] = a02*NSM;
    s_hs[ee1][ww] = a10*NSM; s_hs[ee1][ww+32] = a11*NSM; s_hs[ee1][ww+64] = a12*NSM;
    __syncthreads();   // GEMM reads of b1/b2 done -> safe to reuse

    // p[e][v*32+w] = sum_u xs[u]*Wsv[u][v][w]   (thread t = one vw, 16 edges)
    {
        float p[ETILE];
        #pragma unroll
        for (int e = 0; e < ETILE; ++e) p[e] = 0.f;
        for (int u = 0; u < 64; ++u) {
            float wt = Wsv[u*256 + t];
            #pragma unroll
            for (int e = 0; e < ETILE; ++e) p[e] = fmaf(s_xs[e][u], wt, p[e]);
        }
        #pragma unroll
        for (int e = 0; e < ETILE; ++e) s_b2[e*257 + t] = p[e];
    }
    // vs path in two w-halves: r[e][u][wp] = sum_v es[v]*Wvs[u][v][wh*16+wp]
    for (int wh = 0; wh < 2; ++wh) {
        if (wh) __syncthreads();
        for (int i = t; i < 512; i += 256) {
            int u = i >> 4, wp = i & 15;
            float wv[8];
            #pragma unroll
            for (int v = 0; v < 8; ++v) wv[v] = Wvs[u*256 + v*32 + wh*16 + wp];
            #pragma unroll
            for (int e = 0; e < ETILE; ++e) {
                float acc = 0.f;
                #pragma unroll
                for (int v = 0; v < 8; ++v) acc = fmaf(s_es[e][v], wv[v], acc);
                s_b1[(e*32 + u)*16 + wp] = acc;
            }
        }
        __syncthreads();
        // hv[e][w][k] = sum_v ev[v][k]*p[e][v][w] + sum_u xv[u][k]*r[e][u][wp]
        for (int i = t; i < ETILE*48; i += 256) {
            int e = i / 48, rem = i - e*48, wp = rem / 3, k = rem - wp*3;
            int w = wh*16 + wp;
            float acc = 0.f;
            #pragma unroll
            for (int v = 0; v < 8; ++v) acc = fmaf(s_ev[e][v*3+k], s_b2[e*257 + v*32 + w], acc);
            #pragma unroll
            for (int u = 0; u < 32; ++u) acc = fmaf(s_xv[e][u*3+k], s_b1[(e*32+u)*16 + wp], acc);
            s_hv[e][w*3+k] = acc * NSM;  // n_v = 1/sqrt(768) too
        }
    }
    __syncthreads();

    // gate + scatter (pre-linear): gs 64 + gv 96 floats per edge
    for (int i = t; i < ETILE*64; i += 256) {
        int e = i >> 6, w = i & 63;
        float h = s_hs[e][w];
        atomicAdd(&agg[(size_t)s_row[e]*160 + w], h * sigf(h));
    }
    for (int i = t; i < ETILE*96; i += 256) {
        int e = i / 96, wk = i - e*96, w = wk/3;
        float gate = sigf(s_hs[e][64 + w]);
        atomicAdd(&agg[(size_t)s_row[e]*160 + 64 + wk], s_hv[e][wk] * gate);
    }
}

// =============== aggregated-message irrep linear (commuted past segment_sum) ===============
__global__ __launch_bounds__(128)
void agglin_kernel(const float* __restrict__ agg, const float* __restrict__ Wlms,
                   const float* __restrict__ Wlmv, float* __restrict__ agl)
{
    const int n = blockIdx.x, t = threadIdx.x;
    __shared__ float s_in[160];
    for (int i = t; i < 160; i += 128) s_in[i] = agg[(size_t)n*160 + i];
    __syncthreads();
    if (t < 96) {
        float acc = 0.f;
        #pragma unroll
        for (int u = 0; u < 64; ++u) acc = fmaf(s_in[u], Wlms[u*96 + t], acc);
        agl[(size_t)n*192 + t] = acc * 0.125f;                 // 1/sqrt(64)
    } else {
        int w = t - 96;
        float a0=0.f,a1=0.f,a2=0.f;
        #pragma unroll
        for (int u = 0; u < 32; ++u) {
            float wt = Wlmv[u*32 + w];
            a0 = fmaf(s_in[64+u*3+0], wt, a0);
            a1 = fmaf(s_in[64+u*3+1], wt, a1);
            a2 = fmaf(s_in[64+u*3+2], wt, a2);
        }
        const float s = 0.17677669529663687f;                  // 1/sqrt(32)
        agl[(size_t)n*192 + 96 + w*3 + 0] = a0*s;
        agl[(size_t)n*192 + 96 + w*3 + 1] = a1*s;
        agl[(size_t)n*192 + 96 + w*3 + 2] = a2*s;
    }
}

// =============== update kernel: per-node TP + gate + linear + residual ===============
__global__ __launch_bounds__(256, 2)
void upd_kernel(const float* __restrict__ nf, const float* __restrict__ agl,
                const float* __restrict__ Wss, const float* __restrict__ Wvv,
                const float* __restrict__ Wsv, const float* __restrict__ Wvs,
                const float* __restrict__ Wls, const float* __restrict__ Wlv,
                float* __restrict__ out)
{
    const int n0 = blockIdx.x * NTILE;
    const int t  = threadIdx.x;
    __shared__ float s_xs[NTILE][65];
    __shared__ float s_xv[NTILE][97];
    __shared__ float s_as[NTILE][97];
    __shared__ float s_av[NTILE][97];
    __shared__ float s_hs[NTILE][97];
    __shared__ float s_z[NTILE * 513];

    for (int i = t; i < NTILE*160; i += 256) {
        int n = i / 160, c = i - n*160;
        float v = nf[(size_t)(n0+n)*160 + c];
        if (c < 64) s_xs[n][c] = v; else s_xv[n][c-64] = v;
    }
    for (int i = t; i < NTILE*192; i += 256) {
        int n = i / 192, c = i - n*192;
        float v = agl[(size_t)(n0+n)*192 + c];
        if (c < 96) s_as[n][c] = v; else s_av[n][c-96] = v;
    }

    // hs: K = 6144 (ss) + 1024 (vv, inv_sqrt3 folded into z), chunks of 512
    const int ng = t >> 5, ww = t & 31;
    const int nA = ng, nB = ng + 8;
    float a00=0.f,a01=0.f,a02=0.f,a10=0.f,a11=0.f,a12=0.f;
    for (int ch = 0; ch < 14; ++ch) {
        __syncthreads();
        for (int j = t; j < NTILE*512; j += 256) {
            int n = j >> 9, kk = j & 511;
            int K = ch*512 + kk;
            float z;
            if (K < 6144) {
                int u = K / 96, v = K - u*96;
                z = s_xs[n][u] * s_as[n][v];
            } else {
                int uv = K - 6144, u = uv >> 5, v = uv & 31;
                z = 0.57735026918962576f * (s_xv[n][u*3+0]*s_av[n][v*3+0]
                  + s_xv[n][u*3+1]*s_av[n][v*3+1] + s_xv[n][u*3+2]*s_av[n][v*3+2]);
            }
            s_z[n*513 + kk] = z;
        }
        __syncthreads();
        const float* Wp = (ch < 12) ? (Wss + (size_t)ch*512*96) : (Wvv + (size_t)(ch-12)*512*96);
        #pragma unroll 4
        for (int kk = 0; kk < 512; ++kk) {
            float w0 = Wp[kk*96+ww], w1 = Wp[kk*96+ww+32], w2 = Wp[kk*96+ww+64];
            float z0 = s_z[nA*513+kk], z1 = s_z[nB*513+kk];
            a00=fmaf(z0,w0,a00); a01=fmaf(z0,w1,a01); a02=fmaf(z0,w2,a02);
            a10=fmaf(z1,w0,a10); a11=fmaf(z1,w1,a11); a12=fmaf(z1,w2,a12);
        }
    }
    const float NSU = 0.0118113654f;  // 1/sqrt(7168)
    s_hs[nA][ww]=a00*NSU; s_hs[nA][ww+32]=a01*NSU; s_hs[nA][ww+64]=a02*NSU;
    s_hs[nB][ww]=a10*NSU; s_hs[nB][ww+32]=a11*NSU; s_hs[nB][ww+64]=a12*NSU;

    // hv accumulators: wk = ww + j*32 for nodes nA,nB
    float h0A=0.f,h1A=0.f,h2A=0.f,h0B=0.f,h1B=0.f,h2B=0.f;
    // SV: p2[n][v][w] = sum_u xs[u]*Wsv[u][v][w], two v-halves
    for (int vh = 0; vh < 2; ++vh) {
        __syncthreads();
        {
            int vp = t >> 5, w = t & 31;
            for (int rep = 0; rep < 2; ++rep) {
                int vq = vh*16 + vp + rep*8;
                float pa[NTILE];
                #pragma unroll
                for (int n = 0; n < NTILE; ++n) pa[n] = 0.f;
                for (int u = 0; u < 64; ++u) {
                    float wt = Wsv[u*1024 + vq*32 + w];
                    #pragma unroll
                    for (int n = 0; n < NTILE; ++n) pa[n] = fmaf(s_xs[n][u], wt, pa[n]);
                }
                #pragma unroll
                for (int n = 0; n < NTILE; ++n) s_z[(n*16 + vp + rep*8)*32 + w] = pa[n];
            }
        }
        __syncthreads();
        #pragma unroll
        for (int j = 0; j < 3; ++j) {
            int wk = ww + j*32, w = wk/3, k = wk - w*3;
            float accA = 0.f, accB = 0.f;
            #pragma unroll
            for (int vp = 0; vp < 16; ++vp) {
                accA = fmaf(s_av[nA][(vh*16+vp)*3 + k], s_z[(nA*16+vp)*32 + w], accA);
                accB = fmaf(s_av[nB][(vh*16+vp)*3 + k], s_z[(nB*16+vp)*32 + w], accB);
            }
            if (j==0){h0A+=accA;h0B+=accB;} else if (j==1){h1A+=accA;h1B+=accB;} else {h2A+=accA;h2B+=accB;}
        }
    }
    // VS: r2[n][u][w] = sum_v ags[v]*Wvs[u][v][w], two u-halves
    for (int uh = 0; uh < 2; ++uh) {
        __syncthreads();
        {
            int up = t >> 5, w = t & 31;
            for (int rep = 0; rep < 2; ++rep) {
                int uq = uh*16 + up + rep*8;
                float ra[NTILE];
                #pragma unroll
                for (int n = 0; n < NTILE; ++n) ra[n] = 0.f;
                for (int v = 0; v < 96; ++v) {
                    float wt = Wvs[uq*3072 + v*32 + w];
                    #pragma unroll
                    for (int n = 0; n < NTILE; ++n) ra[n] = fmaf(s_as[n][v], wt, ra[n]);
                }
                #pragma unroll
                for (int n = 0; n < NTILE; ++n) s_z[(n*16 + up + rep*8)*32 + w] = ra[n];
            }
        }
        __syncthreads();
        #pragma unroll
        for (int j = 0; j < 3; ++j) {
            int wk = ww + j*32, w = wk/3, k = wk - w*3;
            float accA = 0.f, accB = 0.f;
            #pragma unroll
            for (int up = 0; up < 16; ++up) {
                accA = fmaf(s_xv[nA][(uh*16+up)*3 + k], s_z[(nA*16+up)*32 + w], accA);
                accB = fmaf(s_xv[nB][(uh*16+up)*3 + k], s_z[(nB*16+up)*32 + w], accB);
            }
            if (j==0){h0A+=accA;h0B+=accB;} else if (j==1){h1A+=accA;h1B+=accB;} else {h2A+=accA;h2B+=accB;}
        }
    }

    // gate + stage gs2/gv2 (reuse s_z)
    float* s_gs2 = s_z;               // [n*65 + w]
    float* s_gv2 = s_z + NTILE*65;    // [n*97 + wk]
    __syncthreads();
    const float NVU = 0.0139754249f;  // 1/sqrt(5120)
    {
        #pragma unroll
        for (int j = 0; j < 3; ++j) {
            int wk = ww + j*32, w = wk/3;
            float hA = (j==0?h0A:(j==1?h1A:h2A)) * NVU;
            float hB = (j==0?h0B:(j==1?h1B:h2B)) * NVU;
            s_gv2[nA*97 + wk] = hA * sigf(s_hs[nA][64 + w]);
            s_gv2[nB*97 + wk] = hB * sigf(s_hs[nB][64 + w]);
        }
    }
    for (int i = t; i < NTILE*64; i += 256) {
        int n = i >> 6, w = i & 63;
        float h = s_hs[n][w];
        s_gs2[n*65 + w] = h * sigf(h);
    }
    __syncthreads();
    // final linear + residual
    for (int i = t; i < NTILE*64; i += 256) {
        int n = i >> 6, w = i & 63;
        float acc = 0.f;
        #pragma unroll
        for (int u = 0; u < 64; ++u) acc = fmaf(s_gs2[n*65+u], Wls[u*64 + w], acc);
        size_t o = (size_t)(n0+n)*160 + w;
        out[o] = nf[o] + acc * 0.125f;
    }
    for (int i = t; i < NTILE*96; i += 256) {
        int n = i / 96, wk = i - n*96, w = wk/3, k = wk - w*3;
        float acc = 0.f;
        #pragma unroll
        for (int u = 0; u < 32; ++u) acc = fmaf(s_gv2[n*97 + u*3 + k], Wlv[u*32 + w], acc);
        size_t o = (size_t)(n0+n)*160 + 64 + wk;
        out[o] = nf[o] + acc * 0.17677669529663687f;
    }
}

extern "C" void kernel_launch(void* const* d_in, const int* in_sizes, int n_in,
                              void* d_out, int out_size, void* d_ws, size_t ws_size,
                              hipStream_t stream) {
    const float* nf   = (const float*)d_in[0];
    const float* ea   = (const float*)d_in[1];
    // d_in[2] node_attr_scalar_raw: unused by reference
    const int*   eidx = (const int*)d_in[3];
    const float* Wmss = (const float*)d_in[4];
    const float* Wmvv = (const float*)d_in[5];
    const float* Wmsv = (const float*)d_in[6];
    const float* Wmvs = (const float*)d_in[7];
    const float* Wlms = (const float*)d_in[8];
    const float* Wlmv = (const float*)d_in[9];
    const float* Wuss = (const float*)d_in[10];
    const float* Wuvv = (const float*)d_in[11];
    const float* Wusv = (const float*)d_in[12];
    const float* Wuvs = (const float*)d_in[13];
    const float* Wlus = (const float*)d_in[14];
    const float* Wluv = (const float*)d_in[15];
    float* out = (float*)d_out;

    float* agg = (float*)d_ws;                       // [NN,160] pre-linear sums
    float* agl = agg + (size_t)NN * 160;             // [NN,192] post-linear ags/agv

    hipMemsetAsync(agg, 0, (size_t)NN * 160 * sizeof(float), stream);
    msg_kernel<<<NE / ETILE, 256, 0, stream>>>(nf, ea, eidx, Wmss, Wmvv, Wmsv, Wmvs, agg);
    agglin_kernel<<<NN, 128, 0, stream>>>(agg, Wlms, Wlmv, agl);
    upd_kernel<<<NN / NTILE, 256, 0, stream>>>(nf, agl, Wuss, Wuvv, Wusv, Wuvs, Wlus, Wluv, out);
}

// Round 2
// 846.003 us; speedup vs baseline: 6.2753x; 6.2753x over previous
//
#include <hip/hip_runtime.h>

#define NN 20000
#define NE 400000

typedef __attribute__((ext_vector_type(8))) short bf8;
typedef __attribute__((ext_vector_type(4))) float f32x4;

__device__ __forceinline__ float sigf(float x) { return 1.0f / (1.0f + __expf(-x)); }

__device__ __forceinline__ short bfc(float f) {
    __bf16 h = (__bf16)f;                // RNE hardware convert
    return __builtin_bit_cast(short, h);
}

// ---------- weight prep: transpose + bf16 + fold norms: dst[w][K] = sc * src[K][w] ----------
__global__ void prep_kernel(const float* __restrict__ s1, const float* __restrict__ s2,
                            int K1, int Kt, int Nw, float sc1, float sc2,
                            unsigned short* __restrict__ dst, int total)
{
    int idx = blockIdx.x * 256 + threadIdx.x;
    if (idx >= total) return;
    int w = idx / Kt, K = idx - w * Kt;
    float v = (K < K1) ? s1[(size_t)K * Nw + w] * sc1
                       : s2[(size_t)(K - K1) * Nw + w] * sc2;
    dst[idx] = (unsigned short)bfc(v);
}

// =============== message kernel: 32 edges/block, MFMA TP + gate + scatter ===============
__global__ __launch_bounds__(256, 2)
void msg_kernel(const float* __restrict__ nf, const float* __restrict__ ea,
                const int* __restrict__ eidx,
                const unsigned short* __restrict__ wA,   // [96][768] bf16, norms folded
                const unsigned short* __restrict__ wB,   // [32][768] bf16, norms folded
                float* __restrict__ agg)
{
    const int e0   = blockIdx.x * 32;
    const int t    = threadIdx.x;
    const int wid  = t >> 6;
    const int lane = t & 63;
    const int ln   = lane & 15;
    const int okt  = lane >> 4;

    __shared__ float s_xs[32][65];
    __shared__ float s_xv[32][97];      // [e][u*3+k]
    __shared__ float s_es[32][12];      // [e][v] (8 used)
    __shared__ float s_evT[32][3][12];  // [e][k][v]
    __shared__ float s_hs[32][97];
    __shared__ int   s_row[32];
    __shared__ int   s_col[32];

    if (t < 32) s_row[t] = eidx[e0 + t];
    else if (t < 64) s_col[t - 32] = eidx[NE + e0 + t - 32];
    for (int i = t; i < 32 * 32; i += 256) {
        int e = i >> 5, c = i & 31;
        float v = ea[(size_t)(e0 + e) * 32 + c];
        if (c < 8) s_es[e][c] = v;
        else { int d = c - 8; s_evT[e][d % 3][d / 3] = v; }
    }
    __syncthreads();
    for (int i = t; i < 32 * 40; i += 256) {
        int e = i / 40, q = i - e * 40;
        f32x4 f4 = *((const f32x4*)nf + (size_t)s_col[e] * 40 + q);
        if (q < 16) {
            #pragma unroll
            for (int j = 0; j < 4; ++j) s_xs[e][q * 4 + j] = f4[j];
        } else {
            #pragma unroll
            for (int j = 0; j < 4; ++j) s_xv[e][(q - 16) * 4 + j] = f4[j];
        }
    }
    __syncthreads();

    f32x4 acc[6] = {};   // wid<2: [m2][j] ; wid>=2: [m]

    if (wid < 2) {
        // GEMM A: hs[32 x 96] = z_A[32 x 768] @ WA^T. Wave owns 3 N-tiles.
        const unsigned short* WT = wA + (size_t)(wid * 48 + ln) * 768;
        for (int ks = 0; ks < 24; ++ks) {
            const int ko = ks * 32 + okt * 8;
            bf8 b0 = *(const bf8*)(WT + ko);
            bf8 b1 = *(const bf8*)(WT + 16 * 768 + ko);
            bf8 b2 = *(const bf8*)(WT + 32 * 768 + ko);
            bf8 a[2];
            #pragma unroll
            for (int m2 = 0; m2 < 2; ++m2) {
                int e = m2 * 16 + ln;
                bf8 av;
                if (ks < 16) {                       // z_ss: xs[u]*es[v]
                    int u = ks * 4 + okt;
                    float x = s_xs[e][u];
                    f32x4 lo = *(const f32x4*)&s_es[e][0];
                    f32x4 hi = *(const f32x4*)&s_es[e][4];
                    #pragma unroll
                    for (int j = 0; j < 4; ++j) { av[j] = bfc(x * lo[j]); av[j + 4] = bfc(x * hi[j]); }
                } else {                              // dd: sum_k xv[u][k]*ev[v][k]
                    int u = (ks - 16) * 4 + okt;
                    float x0 = s_xv[e][u * 3 + 0], x1 = s_xv[e][u * 3 + 1], x2 = s_xv[e][u * 3 + 2];
                    f32x4 e0l = *(const f32x4*)&s_evT[e][0][0], e0h = *(const f32x4*)&s_evT[e][0][4];
                    f32x4 e1l = *(const f32x4*)&s_evT[e][1][0], e1h = *(const f32x4*)&s_evT[e][1][4];
                    f32x4 e2l = *(const f32x4*)&s_evT[e][2][0], e2h = *(const f32x4*)&s_evT[e][2][4];
                    #pragma unroll
                    for (int j = 0; j < 4; ++j) {
                        av[j]     = bfc(x0 * e0l[j] + x1 * e1l[j] + x2 * e2l[j]);
                        av[j + 4] = bfc(x0 * e0h[j] + x1 * e1h[j] + x2 * e2h[j]);
                    }
                }
                a[m2] = av;
            }
            acc[0] = __builtin_amdgcn_mfma_f32_16x16x32_bf16(a[0], b0, acc[0], 0, 0, 0);
            acc[1] = __builtin_amdgcn_mfma_f32_16x16x32_bf16(a[0], b1, acc[1], 0, 0, 0);
            acc[2] = __builtin_amdgcn_mfma_f32_16x16x32_bf16(a[0], b2, acc[2], 0, 0, 0);
            acc[3] = __builtin_amdgcn_mfma_f32_16x16x32_bf16(a[1], b0, acc[3], 0, 0, 0);
            acc[4] = __builtin_amdgcn_mfma_f32_16x16x32_bf16(a[1], b1, acc[4], 0, 0, 0);
            acc[5] = __builtin_amdgcn_mfma_f32_16x16x32_bf16(a[1], b2, acc[5], 0, 0, 0);
        }
        #pragma unroll
        for (int m2 = 0; m2 < 2; ++m2)
            #pragma unroll
            for (int j = 0; j < 3; ++j)
                #pragma unroll
                for (int r = 0; r < 4; ++r)
                    s_hs[m2 * 16 + okt * 4 + r][wid * 48 + j * 16 + ln] = acc[m2 * 3 + j][r];
    } else {
        // GEMM B: hv[(k,e)=96 x 32] = z_B @ WB^T. Wave owns 1 N-tile, 6 M-tiles.
        const unsigned short* WT = wB + (size_t)((wid - 2) * 16 + ln) * 768;
        for (int ks = 0; ks < 24; ++ks) {
            const int ko = ks * 32 + okt * 8;
            bf8 b = *(const bf8*)(WT + ko);
            #pragma unroll
            for (int m = 0; m < 6; ++m) {
                int k3 = m >> 1, e = (m & 1) * 16 + ln;
                bf8 av;
                if (ks < 16) {                       // z2: xs[u]*ev[v][k3]
                    int u = ks * 4 + okt;
                    float x = s_xs[e][u];
                    f32x4 lo = *(const f32x4*)&s_evT[e][k3][0];
                    f32x4 hi = *(const f32x4*)&s_evT[e][k3][4];
                    #pragma unroll
                    for (int j = 0; j < 4; ++j) { av[j] = bfc(x * lo[j]); av[j + 4] = bfc(x * hi[j]); }
                } else {                              // z3: xv[u][k3]*es[v]
                    int u = (ks - 16) * 4 + okt;
                    float x = s_xv[e][u * 3 + k3];
                    f32x4 lo = *(const f32x4*)&s_es[e][0];
                    f32x4 hi = *(const f32x4*)&s_es[e][4];
                    #pragma unroll
                    for (int j = 0; j < 4; ++j) { av[j] = bfc(x * lo[j]); av[j + 4] = bfc(x * hi[j]); }
                }
                acc[m] = __builtin_amdgcn_mfma_f32_16x16x32_bf16(av, b, acc[m], 0, 0, 0);
            }
        }
    }
    __syncthreads();

    if (wid < 2) {
        // silu scalars, scatter: 32 edges x 64 w over 128 threads
        int t2 = wid * 64 + lane;
        #pragma unroll
        for (int r = 0; r < 16; ++r) {
            int idx = t2 + r * 128, e = idx >> 6, w = idx & 63;
            float h = s_hs[e][w];
            atomicAdd(agg + (size_t)s_row[e] * 160 + w, h * sigf(h));
        }
    } else {
        int w = (wid - 2) * 16 + ln;
        #pragma unroll
        for (int m = 0; m < 6; ++m) {
            int k3 = m >> 1;
            #pragma unroll
            for (int r = 0; r < 4; ++r) {
                int e = (m & 1) * 16 + okt * 4 + r;
                float g = sigf(s_hs[e][64 + w]);
                atomicAdd(agg + (size_t)s_row[e] * 160 + 64 + w * 3 + k3, acc[m][r] * g);
            }
        }
    }
}

// =============== aggregated-message irrep linear (commuted past segment_sum) ===============
__global__ __launch_bounds__(128)
void agglin_kernel(const float* __restrict__ agg, const float* __restrict__ Wlms,
                   const float* __restrict__ Wlmv, float* __restrict__ agl)
{
    const int n = blockIdx.x, t = threadIdx.x;
    __shared__ float s_in[160];
    for (int i = t; i < 160; i += 128) s_in[i] = agg[(size_t)n * 160 + i];
    __syncthreads();
    if (t < 96) {
        float acc = 0.f;
        #pragma unroll
        for (int u = 0; u < 64; ++u) acc = fmaf(s_in[u], Wlms[u * 96 + t], acc);
        agl[(size_t)n * 192 + t] = acc * 0.125f;
    } else {
        int w = t - 96;
        float a0 = 0.f, a1 = 0.f, a2 = 0.f;
        #pragma unroll
        for (int u = 0; u < 32; ++u) {
            float wt = Wlmv[u * 32 + w];
            a0 = fmaf(s_in[64 + u * 3 + 0], wt, a0);
            a1 = fmaf(s_in[64 + u * 3 + 1], wt, a1);
            a2 = fmaf(s_in[64 + u * 3 + 2], wt, a2);
        }
        const float s = 0.17677669529663687f;
        agl[(size_t)n * 192 + 96 + w * 3 + 0] = a0 * s;
        agl[(size_t)n * 192 + 96 + w * 3 + 1] = a1 * s;
        agl[(size_t)n * 192 + 96 + w * 3 + 2] = a2 * s;
    }
}

// =============== update kernel: 16 nodes/block, MFMA TP + gate + linear + residual ===============
__global__ __launch_bounds__(256, 2)
void upd_kernel(const float* __restrict__ nf, const float* __restrict__ agl,
                const unsigned short* __restrict__ wA,   // [96][7168]
                const unsigned short* __restrict__ wB,   // [32][5120]
                const float* __restrict__ Wls, const float* __restrict__ Wlv,
                float* __restrict__ out)
{
    const int n0   = blockIdx.x * 16;
    const int t    = threadIdx.x;
    const int wid  = t >> 6;
    const int lane = t & 63;
    const int ln   = lane & 15;
    const int okt  = lane >> 4;

    __shared__ float s_xs[16][65];
    __shared__ float s_xv[16][97];
    __shared__ float s_as[16][100];      // ags, stride 100 for banks
    __shared__ float s_avT[16][3][36];   // [n][k][v]
    __shared__ float s_hs[16][97];
    __shared__ float s_gs2[16][65];
    __shared__ float s_gv2[16][97];

    for (int i = t; i < 16 * 40; i += 256) {
        int n = i / 40, q = i - n * 40;
        f32x4 f4 = *((const f32x4*)nf + (size_t)(n0 + n) * 40 + q);
        if (q < 16) {
            #pragma unroll
            for (int j = 0; j < 4; ++j) s_xs[n][q * 4 + j] = f4[j];
        } else {
            #pragma unroll
            for (int j = 0; j < 4; ++j) s_xv[n][(q - 16) * 4 + j] = f4[j];
        }
    }
    for (int i = t; i < 16 * 192; i += 256) {
        int n = i / 192, c = i - n * 192;
        float v = agl[(size_t)(n0 + n) * 192 + c];
        if (c < 96) s_as[n][c] = v;
        else { int wk = c - 96; s_avT[n][wk % 3][wk / 3] = v; }
    }
    __syncthreads();

    f32x4 acc[3] = {};

    if (wid < 2) {
        // hs2: [16 x 96] = z[16 x 7168] @ WAu^T. Wave owns 3 N-tiles, K=224 steps.
        const unsigned short* WT = wA + (size_t)(wid * 48 + ln) * 7168;
        for (int ks = 0; ks < 224; ++ks) {
            const int ko = ks * 32 + okt * 8;
            bf8 b0 = *(const bf8*)(WT + ko);
            bf8 b1 = *(const bf8*)(WT + 16 * 7168 + ko);
            bf8 b2 = *(const bf8*)(WT + 32 * 7168 + ko);
            bf8 av;
            if (ks < 192) {                           // ss: xs[u]*ags[v]
                int u = ko / 96, v0 = ko - u * 96;
                float x = s_xs[ln][u];
                f32x4 lo = *(const f32x4*)&s_as[ln][v0];
                f32x4 hi = *(const f32x4*)&s_as[ln][v0 + 4];
                #pragma unroll
                for (int j = 0; j < 4; ++j) { av[j] = bfc(x * lo[j]); av[j + 4] = bfc(x * hi[j]); }
            } else {                                   // vv: sum_k xv[u][k]*agv[v][k]
                int kp = ko - 6144;
                int u = kp >> 5, v0 = kp & 31;
                float x0 = s_xv[ln][u * 3 + 0], x1 = s_xv[ln][u * 3 + 1], x2 = s_xv[ln][u * 3 + 2];
                f32x4 a0l = *(const f32x4*)&s_avT[ln][0][v0], a0h = *(const f32x4*)&s_avT[ln][0][v0 + 4];
                f32x4 a1l = *(const f32x4*)&s_avT[ln][1][v0], a1h = *(const f32x4*)&s_avT[ln][1][v0 + 4];
                f32x4 a2l = *(const f32x4*)&s_avT[ln][2][v0], a2h = *(const f32x4*)&s_avT[ln][2][v0 + 4];
                #pragma unroll
                for (int j = 0; j < 4; ++j) {
                    av[j]     = bfc(x0 * a0l[j] + x1 * a1l[j] + x2 * a2l[j]);
                    av[j + 4] = bfc(x0 * a0h[j] + x1 * a1h[j] + x2 * a2h[j]);
                }
            }
            acc[0] = __builtin_amdgcn_mfma_f32_16x16x32_bf16(av, b0, acc[0], 0, 0, 0);
            acc[1] = __builtin_amdgcn_mfma_f32_16x16x32_bf16(av, b1, acc[1], 0, 0, 0);
            acc[2] = __builtin_amdgcn_mfma_f32_16x16x32_bf16(av, b2, acc[2], 0, 0, 0);
        }
        #pragma unroll
        for (int j = 0; j < 3; ++j)
            #pragma unroll
            for (int r = 0; r < 4; ++r)
                s_hs[okt * 4 + r][wid * 48 + j * 16 + ln] = acc[j][r];
    } else {
        // hv2: [(k,n)=48 x 32] = zB[48 x 5120] @ WBu^T. Wave owns 1 N-tile, 3 M-tiles.
        const unsigned short* WT = wB + (size_t)((wid - 2) * 16 + ln) * 5120;
        for (int ks = 0; ks < 160; ++ks) {
            const int ko = ks * 32 + okt * 8;
            bf8 b = *(const bf8*)(WT + ko);
            #pragma unroll
            for (int m = 0; m < 3; ++m) {
                bf8 av;
                if (ks < 64) {                        // z2: xs[u]*agv[v][m]
                    int u = ko >> 5, v0 = ko & 31;
                    float x = s_xs[ln][u];
                    f32x4 lo = *(const f32x4*)&s_avT[ln][m][v0];
                    f32x4 hi = *(const f32x4*)&s_avT[ln][m][v0 + 4];
                    #pragma unroll
                    for (int j = 0; j < 4; ++j) { av[j] = bfc(x * lo[j]); av[j + 4] = bfc(x * hi[j]); }
                } else {                               // z3: xv[u][m]*ags[v]
                    int kp = ko - 2048;
                    int u = kp / 96, v0 = kp - u * 96;
                    float x = s_xv[ln][u * 3 + m];
                    f32x4 lo = *(const f32x4*)&s_as[ln][v0];
                    f32x4 hi = *(const f32x4*)&s_as[ln][v0 + 4];
                    #pragma unroll
                    for (int j = 0; j < 4; ++j) { av[j] = bfc(x * lo[j]); av[j + 4] = bfc(x * hi[j]); }
                }
                acc[m] = __builtin_amdgcn_mfma_f32_16x16x32_bf16(av, b, acc[m], 0, 0, 0);
            }
        }
    }
    __syncthreads();

    for (int i = t; i < 16 * 64; i += 256) {
        int n = i >> 6, w = i & 63;
        float h = s_hs[n][w];
        s_gs2[n][w] = h * sigf(h);
    }
    if (wid >= 2) {
        int w = (wid - 2) * 16 + ln;
        #pragma unroll
        for (int m = 0; m < 3; ++m)
            #pragma unroll
            for (int r = 0; r < 4; ++r) {
                int n = okt * 4 + r;
                float g = sigf(s_hs[n][64 + w]);
                s_gv2[n][w * 3 + m] = acc[m][r] * g;
            }
    }
    __syncthreads();

    for (int i = t; i < 16 * 64; i += 256) {
        int n = i >> 6, w = i & 63;
        float acc2 = 0.f;
        #pragma unroll
        for (int u = 0; u < 64; ++u) acc2 = fmaf(s_gs2[n][u], Wls[u * 64 + w], acc2);
        size_t o = (size_t)(n0 + n) * 160 + w;
        out[o] = nf[o] + acc2 * 0.125f;
    }
    for (int i = t; i < 16 * 96; i += 256) {
        int n = i / 96, wk = i - n * 96, w = wk / 3, k = wk - w * 3;
        float acc2 = 0.f;
        #pragma unroll
        for (int u = 0; u < 32; ++u) acc2 = fmaf(s_gv2[n][u * 3 + k], Wlv[u * 32 + w], acc2);
        size_t o = (size_t)(n0 + n) * 160 + 64 + wk;
        out[o] = nf[o] + acc2 * 0.17677669529663687f;
    }
}

extern "C" void kernel_launch(void* const* d_in, const int* in_sizes, int n_in,
                              void* d_out, int out_size, void* d_ws, size_t ws_size,
                              hipStream_t stream) {
    const float* nf   = (const float*)d_in[0];
    const float* ea   = (const float*)d_in[1];
    const int*   eidx = (const int*)d_in[3];
    const float* Wmss = (const float*)d_in[4];
    const float* Wmvv = (const float*)d_in[5];
    const float* Wmsv = (const float*)d_in[6];
    const float* Wmvs = (const float*)d_in[7];
    const float* Wlms = (const float*)d_in[8];
    const float* Wlmv = (const float*)d_in[9];
    const float* Wuss = (const float*)d_in[10];
    const float* Wuvv = (const float*)d_in[11];
    const float* Wusv = (const float*)d_in[12];
    const float* Wuvs = (const float*)d_in[13];
    const float* Wlus = (const float*)d_in[14];
    const float* Wluv = (const float*)d_in[15];
    float* out = (float*)d_out;

    float* agg = (float*)d_ws;                          // [NN,160]
    float* agl = agg + (size_t)NN * 160;                // [NN,192]
    unsigned short* wAm = (unsigned short*)(agl + (size_t)NN * 192);
    unsigned short* wBm = wAm + 96 * 768;
    unsigned short* wAu = wBm + 32 * 768;
    unsigned short* wBu = wAu + (size_t)96 * 7168;

    const float NSM = 0.03608439182435161f;   // 1/sqrt(768)
    const float NSU = 0.011811365506297619f;  // 1/sqrt(7168)
    const float NVU = 0.013975424859373686f;  // 1/sqrt(5120)
    const float S3  = 0.57735026918962576f;   // 1/sqrt(3)

    prep_kernel<<<(96 * 768 + 255) / 256, 256, 0, stream>>>(Wmss, Wmvv, 512, 768, 96, NSM, NSM * S3, wAm, 96 * 768);
    prep_kernel<<<(32 * 768 + 255) / 256, 256, 0, stream>>>(Wmsv, Wmvs, 512, 768, 32, NSM, NSM, wBm, 32 * 768);
    prep_kernel<<<(96 * 7168 + 255) / 256, 256, 0, stream>>>(Wuss, Wuvv, 6144, 7168, 96, NSU, NSU * S3, wAu, 96 * 7168);
    prep_kernel<<<(32 * 5120 + 255) / 256, 256, 0, stream>>>(Wusv, Wuvs, 2048, 5120, 32, NVU, NVU, wBu, 32 * 5120);

    hipMemsetAsync(agg, 0, (size_t)NN * 160 * sizeof(float), stream);
    msg_kernel<<<NE / 32, 256, 0, stream>>>(nf, ea, eidx, wAm, wBm, agg);
    agglin_kernel<<<NN, 128, 0, stream>>>(agg, Wlms, Wlmv, agl);
    upd_kernel<<<NN / 16, 256, 0, stream>>>(nf, agl, wAu, wBu, Wlus, Wluv, out);
}